// Round 13
// baseline (139.330 us; speedup 1.0000x reference)
//
#include <hip/hip_runtime.h>
#include <hip/hip_bf16.h>
#include <math.h>

#define B_ 2
#define L_ 2048
#define D_ 1024
#define N_ 16
#define CCH 64   // chunks over L
#define TCH 32   // chunk length  (CCH*TCH == L_)
#define NCOLS 1056   // D_ + 2*N_
#define NPAD  1088   // 17 * 64

typedef unsigned short u16;
typedef __attribute__((ext_vector_type(8))) short short8v;
typedef __attribute__((ext_vector_type(8))) unsigned short ushort8v;
typedef __attribute__((ext_vector_type(4))) float f32x4;

__device__ __forceinline__ float softplusf(float z) {
  return fmaxf(z, 0.f) + log1pf(__expf(-fabsf(z)));
}

__device__ __forceinline__ u16 bf16rne(float f) {
  union { float f; unsigned u; } c; c.f = f;
  unsigned u = c.u;
  u += 0x7fffu + ((u >> 16) & 1u);
  return (u16)(u >> 16);
}

__device__ __forceinline__ float bf16tof(u16 v) {
  union { unsigned u; float f; } c;
  c.u = (unsigned)v << 16;
  return c.f;
}

__device__ __forceinline__ void gl_lds16(const void* g, const u16* lds_base,
                                         int byte_off) {
  byte_off = __builtin_amdgcn_readfirstlane(byte_off);
  __builtin_amdgcn_global_load_lds(
      (const __attribute__((address_space(1))) void*)g,
      (__attribute__((address_space(3))) void*)((const char*)lds_base + byte_off),
      16, 0, 0);
}

// ------------- K1: fused gc partial-sum + x -> bf16 pack ---------------------
__global__ __launch_bounds__(256) void k_gc_pack(const float* __restrict__ x,
    float* __restrict__ part1, u16* __restrict__ xb) {
  int blk = blockIdx.x;
  int b = blk >> 8, lc = blk & 255;
  int tid = threadIdx.x;
  int r0 = b * L_ + lc * 8;
  float4 s = {0.f, 0.f, 0.f, 0.f};
  #pragma unroll
  for (int q = 0; q < 8; ++q) {
    size_t off = (size_t)(r0 + q) * D_ + tid * 4;
    float4 v = *(const float4*)(x + off);
    s.x += v.x; s.y += v.y; s.z += v.z; s.w += v.w;
    ushort4 r;
    r.x = bf16rne(v.x); r.y = bf16rne(v.y);
    r.z = bf16rne(v.z); r.w = bf16rne(v.w);
    *(ushort4*)(xb + off) = r;
  }
  *(float4*)(part1 + (size_t)blk * D_ + tid * 4) = s;
}

// ------------- K1b: reduce part1[512][1024] -> part2[2][16][1024] ------------
__global__ __launch_bounds__(256) void k_gc_red(const float* __restrict__ part1,
                                                float* __restrict__ part2) {
  int gid = blockIdx.x * 256 + threadIdx.x;   // 32768 = (b, jc, d)
  int d = gid & 1023;
  int jc = (gid >> 10) & 15;
  int b = gid >> 14;
  float s = 0.f;
  #pragma unroll
  for (int t = 0; t < 16; ++t)
    s += part1[(size_t)(b * 256 + jc * 16 + t) * D_ + d];
  part2[gid] = s;
}

// ------------- K2: gc -> liquid scaler -> new_h -> sel (fused) ---------------
__global__ __launch_bounds__(256) void k_newh_sel(const float* __restrict__ part2,
    const float* __restrict__ Wi_W, const float* __restrict__ Wi_b,
    const float* __restrict__ Wr_W, const float* __restrict__ tau,
    const float* __restrict__ h0, const float* __restrict__ sel_W,
    const float* __restrict__ sel_b, float* __restrict__ selp) {
  __shared__ float gcs[B_ * D_];
  __shared__ float nh[B_ * N_];
  int tid = threadIdx.x;
  for (int idx = tid; idx < B_ * D_; idx += 256) {
    int b = idx >> 10, d = idx & (D_ - 1);
    float s = 0.f;
    #pragma unroll
    for (int lc = 0; lc < 16; ++lc)
      s += part2[(size_t)((b << 4) | lc) * D_ + d];
    gcs[idx] = s * (1.f / L_);
  }
  __syncthreads();
  if (tid < B_ * N_) {
    int b = tid >> 4, n = tid & 15;
    float inp = Wi_b[n];
    const float* g = gcs + b * D_;
    const float* w = Wi_W + n * D_;
    for (int d = 0; d < D_; d += 4) {
      float4 gv = *(const float4*)(g + d);
      float4 wv = *(const float4*)(w + d);
      inp += gv.x * wv.x + gv.y * wv.y + gv.z * wv.z + gv.w * wv.w;
    }
    float rec = 0.f;
    for (int m = 0; m < N_; ++m) rec += h0[m] * Wr_W[n * N_ + m];
    float th = tanhf(inp + rec);
    float tc = fminf(fmaxf(tau[n], 0.1f), 10.f);
    float cur = h0[n];
    nh[tid] = cur + 0.1f * ((th - cur) / tc);   // DT = 0.1
  }
  __syncthreads();
  for (int i = tid; i < B_ * D_; i += 256) {
    int b = i >> 10, d = i & (D_ - 1);
    const float* w = sel_W + d * N_;
    const float* h = nh + b * N_;
    float z = sel_b[d];
    #pragma unroll
    for (int n = 0; n < N_; n += 4) {
      float4 wv = *(const float4*)(w + n);
      z += h[n] * wv.x + h[n + 1] * wv.y + h[n + 2] * wv.z + h[n + 3] * wv.w;
    }
    selp[i] = 1.f / (1.f + __expf(-z));
  }
}

// ------------- K4: pack [delta_W; B_W; C_W] * sel(b) -> bf16 -----------------
__global__ __launch_bounds__(256) void k_pack_w(const float* __restrict__ dW,
    const float* __restrict__ B_W, const float* __restrict__ C_W,
    const float* __restrict__ sel, u16* __restrict__ Wp) {
  int gid = blockIdx.x * 256 + threadIdx.x;    // 139264 threads, 8 elems each
  int b = blockIdx.y;
  size_t e = (size_t)gid * 8;                  // < 1114112
  int nn = (int)(e >> 10);
  int k = (int)(e & 1023);
  ushort8v r;
  if (nn < NCOLS) {
    const float* src = (nn < 1024) ? dW + (size_t)nn * 1024
                     : (nn < 1040) ? B_W + (size_t)(nn - 1024) * 1024
                                   : C_W + (size_t)(nn - 1040) * 1024;
    float4 s0 = *(const float4*)(src + k);
    float4 s1 = *(const float4*)(src + k + 4);
    const float* sp = sel + b * D_ + k;
    float4 e0 = *(const float4*)sp;
    float4 e1 = *(const float4*)(sp + 4);
    r[0] = bf16rne(s0.x * e0.x); r[1] = bf16rne(s0.y * e0.y);
    r[2] = bf16rne(s0.z * e0.z); r[3] = bf16rne(s0.w * e0.w);
    r[4] = bf16rne(s1.x * e1.x); r[5] = bf16rne(s1.y * e1.y);
    r[6] = bf16rne(s1.z * e1.z); r[7] = bf16rne(s1.w * e1.w);
  } else {
    r = (ushort8v)0;
  }
  *(ushort8v*)(Wp + (size_t)b * (NPAD * 1024) + e) = r;
}

// ------------- K5: MFMA GEMM  C[4096 x 1088] = xb @ Wp^T ---------------------
// WAVE-PRIVATE design: each wave owns a 32x32 C-subtile and its own 16 KB LDS
// region (A 32x64 + B 32x64, double-buffered). ZERO barriers — ordering is
// per-wave vmcnt(8) (2 tiles in flight) + lgkmcnt(0)+sched_barrier before
// buffer reuse. Tests the "barrier serialization is the binding constraint"
// hypothesis from R12 (deeper pipeline failed; TLP-only helped).
__global__ __launch_bounds__(256) void k_gemm(
    const u16* __restrict__ xb, const u16* __restrict__ Wp,
    const float* __restrict__ delta_b, const float* __restrict__ dt_bias,
    const float* __restrict__ B_b, const float* __restrict__ C_b,
    float* __restrict__ delta, float* __restrict__ Bm, float* __restrict__ Cm) {
  __shared__ __align__(16) u16 lds[32768];     // 64 KB = 4 waves x 16 KB
  int m0 = blockIdx.x * 64;
  int n0 = blockIdx.y * 64;
  int batch = blockIdx.x >> 5;                 // 32 m-tiles per batch
  const u16* wb = Wp + (size_t)batch * (NPAD * 1024);
  int tid = threadIdx.x;
  int w = tid >> 6, l = tid & 63;
  int wr = w >> 1, wc = w & 1;
  int srow = l >> 3;                           // 0..7
  int ssl = (l & 7) ^ srow;                    // swizzled source 16B slot
  int wbase = w * 16384;                       // this wave's LDS byte base

  f32x4 acc[2][2];
  #pragma unroll
  for (int m = 0; m < 2; ++m)
    #pragma unroll
    for (int n = 0; n < 2; ++n)
      acc[m][n] = (f32x4){0.f, 0.f, 0.f, 0.f};

  // Stage this wave's own A panel (rows m0+wr*32..+32) and B panel
  // (rows n0+wc*32..+32) for K-slice kb: 8 gl_lds, all wave-local.
  #define STAGE(kb, buf)                                                       \
    {                                                                          \
      _Pragma("unroll")                                                        \
      for (int q = 0; q < 4; ++q) {                                            \
        int ra = m0 + wr * 32 + q * 8 + srow;                                  \
        gl_lds16(xb + (size_t)ra * 1024 + (kb) * 64 + ssl * 8,                 \
                 &lds[0], wbase + (buf) * 8192 + q * 1024);                    \
        int rb = n0 + wc * 32 + q * 8 + srow;                                  \
        gl_lds16(wb + (size_t)rb * 1024 + (kb) * 64 + ssl * 8,                 \
                 &lds[0], wbase + (buf) * 8192 + 4096 + q * 1024);             \
      }                                                                        \
    }

  int lr = l & 15, lh = l >> 4;                // lane row / k-quarter
  short8v a_[2][2], b_[2][2];                  // [ks][frag]

  #define CSTEP_READ(buf)                                                      \
    {                                                                          \
      _Pragma("unroll")                                                        \
      for (int ks = 0; ks < 2; ++ks) {                                         \
        _Pragma("unroll")                                                      \
        for (int m = 0; m < 2; ++m) {                                          \
          int r = m * 16 + lr;                                                 \
          int ps = (ks * 4 + lh) ^ (r & 7);                                    \
          a_[ks][m] = *(const short8v*)((const char*)&lds[0] + wbase +         \
                                        (buf) * 8192 + r * 128 + ps * 16);     \
        }                                                                      \
        _Pragma("unroll")                                                      \
        for (int n = 0; n < 2; ++n) {                                          \
          int r = n * 16 + lr;                                                 \
          int ps = (ks * 4 + lh) ^ (r & 7);                                    \
          b_[ks][n] = *(const short8v*)((const char*)&lds[0] + wbase +         \
                                        (buf) * 8192 + 4096 + r * 128 + ps * 16);\
        }                                                                      \
      }                                                                        \
    }

  #define CSTEP_MFMA()                                                         \
    {                                                                          \
      _Pragma("unroll")                                                        \
      for (int ks = 0; ks < 2; ++ks)                                           \
        _Pragma("unroll")                                                      \
        for (int m = 0; m < 2; ++m)                                            \
          _Pragma("unroll")                                                    \
          for (int n = 0; n < 2; ++n)                                          \
            acc[m][n] = __builtin_amdgcn_mfma_f32_16x16x32_bf16(               \
                a_[ks][m], b_[ks][n], acc[m][n], 0, 0, 0);                     \
    }

  STAGE(0, 0);
  STAGE(1, 1);                                 // 16 loads outstanding
  #pragma unroll
  for (int kb = 0; kb < 14; ++kb) {
    asm volatile("s_waitcnt vmcnt(8)" ::: "memory");   // tile kb landed
    CSTEP_READ(kb & 1);
    asm volatile("s_waitcnt lgkmcnt(0)" ::: "memory"); // frags in VGPR
    __builtin_amdgcn_sched_barrier(0);                 // rule #18 fence
    STAGE(kb + 2, kb & 1);                             // reuse buffer safely
    CSTEP_MFMA();
  }
  asm volatile("s_waitcnt vmcnt(8)" ::: "memory");     // tile 14 landed
  CSTEP_READ(0);
  asm volatile("s_waitcnt lgkmcnt(0)" ::: "memory");
  __builtin_amdgcn_sched_barrier(0);
  CSTEP_MFMA();
  asm volatile("s_waitcnt vmcnt(0)" ::: "memory");     // tile 15 landed
  CSTEP_READ(1);
  asm volatile("s_waitcnt lgkmcnt(0)" ::: "memory");
  __builtin_amdgcn_sched_barrier(0);
  CSTEP_MFMA();
  #undef STAGE
  #undef CSTEP_READ
  #undef CSTEP_MFMA

  int ibase = m0 + wr * 32 + lh * 4;
  int jbase = n0 + wc * 32 + lr;
  #pragma unroll
  for (int m = 0; m < 2; ++m) {
    #pragma unroll
    for (int n = 0; n < 2; ++n) {
      int j = jbase + n * 16;
      #pragma unroll
      for (int r = 0; r < 4; ++r) {
        int i = ibase + m * 16 + r;
        float v = acc[m][n][r];
        if (j < 1024) {
          delta[(size_t)i * D_ + j] = softplusf(v + delta_b[j] + dt_bias[j]);
        } else if (j < 1040) {
          Bm[i * N_ + (j - 1024)] = v + B_b[j - 1024];
        } else if (j < NCOLS) {
          Cm[i * N_ + (j - 1040)] = v + C_b[j - 1040];
        }
      }
    }
  }
}

// ------------- K6: scan pass 1 — local scan + decay product ------------------
// 4-way N-split; reads bf16 xb (L2-resident). 2048 blocks, streaming.
__global__ __launch_bounds__(256) void k_scan1(const u16* __restrict__ xb,
    const float* __restrict__ sel, const float* __restrict__ delta,
    const float* __restrict__ Bm, const float* __restrict__ A_log,
    float* __restrict__ prodA, float* __restrict__ hend) {
  int gid = blockIdx.x * 256 + threadIdx.x;   // ((b*CCH+c)*D + d)*4 + nq
  int nq = gid & 3;
  int d = (gid >> 2) & (D_ - 1);
  int c = (gid >> 12) & (CCH - 1);
  int b = gid >> 18;
  float A[4], rA[4];
  unsigned smallm = 0;
  {
    float4 a0 = *(const float4*)(A_log + d * N_ + nq * 4);
    float av[4] = {a0.x, a0.y, a0.z, a0.w};
    #pragma unroll
    for (int n = 0; n < 4; ++n) {
      float a = -__expf(av[n]);
      A[n] = a; rA[n] = 1.f / a;
      if (fabsf(a) < 1e-6f) smallm |= (1u << n);
    }
  }
  float selv = sel[b * D_ + d];
  float h[4], p[4];
  #pragma unroll
  for (int n = 0; n < 4; ++n) { h[n] = 0.f; p[n] = 1.f; }
  int row0 = b * L_ + c * TCH;
  const u16* xp = xb + (size_t)row0 * D_ + d;
  const float* dp = delta + (size_t)row0 * D_ + d;
  const float4* bmp = (const float4*)(Bm + (size_t)row0 * N_) + nq;
  #pragma unroll 4
  for (int s = 0; s < TCH; ++s) {
    float dlt = dp[(size_t)s * D_];
    float xv = bf16tof(xp[(size_t)s * D_]) * selv;
    float4 q0 = bmp[s * 4];
    float bmv[4] = {q0.x, q0.y, q0.z, q0.w};
    #pragma unroll
    for (int n = 0; n < 4; ++n) {
      float Ad = __expf(A[n] * dlt);
      float f = ((smallm >> n) & 1u) ? dlt : (Ad - 1.f) * rA[n];
      h[n] = Ad * h[n] + (f * bmv[n]) * xv;
      p[n] *= Ad;
    }
  }
  size_t base = ((size_t)(gid >> 2)) * N_ + nq * 4;
  *(float4*)(prodA + base) = make_float4(p[0], p[1], p[2], p[3]);
  *(float4*)(hend + base)  = make_float4(h[0], h[1], h[2], h[3]);
}

// ------------- K7: scan pass 2 — cross-chunk prefix (per b,d,n) --------------
__global__ __launch_bounds__(256) void k_scan2(const float* __restrict__ prodA,
    const float* __restrict__ hend, float* __restrict__ hin) {
  int gid = blockIdx.x * 256 + threadIdx.x;   // over B*D*N = 32768
  int b = gid >> 14;
  int rem = gid & 16383;
  size_t base = ((size_t)(b * CCH) << 14) + rem;
  float H = 0.f;
  #pragma unroll
  for (int g = 0; g < 4; ++g) {
    float pg[16], hg[16];
    #pragma unroll
    for (int t = 0; t < 16; ++t) {
      size_t idx = base + ((size_t)(g * 16 + t) << 14);
      pg[t] = prodA[idx];
      hg[t] = hend[idx];
    }
    #pragma unroll
    for (int t = 0; t < 16; ++t) {
      size_t idx = base + ((size_t)(g * 16 + t) << 14);
      hin[idx] = H;
      H = pg[t] * H + hg[t];
    }
  }
}

// ------------- K8: scan pass 3 — re-scan with carry-in, emit y ---------------
// 4-way N-split; reads bf16 xb; y reduced via shfl_xor(1), shfl_xor(2).
__global__ __launch_bounds__(256) void k_scan3(const u16* __restrict__ xb,
    const float* __restrict__ sel, const float* __restrict__ delta,
    const float* __restrict__ Bm, const float* __restrict__ Cm,
    const float* __restrict__ A_log, const float* __restrict__ hin,
    float* __restrict__ out) {
  int gid = blockIdx.x * 256 + threadIdx.x;   // 524288 threads
  int nq = gid & 3;
  int d = (gid >> 2) & (D_ - 1);
  int c = (gid >> 12) & (CCH - 1);
  int b = gid >> 18;
  float A[4], rA[4];
  unsigned smallm = 0;
  {
    float4 a0 = *(const float4*)(A_log + d * N_ + nq * 4);
    float av[4] = {a0.x, a0.y, a0.z, a0.w};
    #pragma unroll
    for (int n = 0; n < 4; ++n) {
      float a = -__expf(av[n]);
      A[n] = a; rA[n] = 1.f / a;
      if (fabsf(a) < 1e-6f) smallm |= (1u << n);
    }
  }
  float selv = sel[b * D_ + d];
  float h[4];
  {
    size_t base = ((size_t)(gid >> 2)) * N_ + nq * 4;
    float4 v0 = *(const float4*)(hin + base);
    h[0] = v0.x; h[1] = v0.y; h[2] = v0.z; h[3] = v0.w;
  }
  int row0 = b * L_ + c * TCH;
  const u16* xp = xb + (size_t)row0 * D_ + d;
  const float* dp = delta + (size_t)row0 * D_ + d;
  const float4* bmp = (const float4*)(Bm + (size_t)row0 * N_) + nq;
  const float4* cmp = (const float4*)(Cm + (size_t)row0 * N_) + nq;
  float* op = out + (size_t)row0 * D_ + d;
  #pragma unroll 4
  for (int s = 0; s < TCH; ++s) {
    float dlt = dp[(size_t)s * D_];
    float xv = bf16tof(xp[(size_t)s * D_]) * selv;
    float4 q0 = bmp[s * 4];
    float4 r0 = cmp[s * 4];
    float bmv[4] = {q0.x, q0.y, q0.z, q0.w};
    float cmv[4] = {r0.x, r0.y, r0.z, r0.w};
    float yp = 0.f;
    #pragma unroll
    for (int n = 0; n < 4; ++n) {
      float Ad = __expf(A[n] * dlt);
      float f = ((smallm >> n) & 1u) ? dlt : (Ad - 1.f) * rA[n];
      h[n] = Ad * h[n] + (f * bmv[n]) * xv;
      yp += h[n] * cmv[n];
    }
    float y = yp + __shfl_xor(yp, 1, 64);
    y += __shfl_xor(y, 2, 64);
    if (nq == 0) op[(size_t)s * D_] = y;
  }
}

extern "C" void kernel_launch(void* const* d_in, const int* in_sizes, int n_in,
                              void* d_out, int out_size, void* d_ws, size_t ws_size,
                              hipStream_t stream) {
  const float* x       = (const float*)d_in[0];
  const float* deltaW  = (const float*)d_in[1];
  const float* deltab  = (const float*)d_in[2];
  const float* B_W     = (const float*)d_in[3];
  const float* B_b     = (const float*)d_in[4];
  const float* C_W     = (const float*)d_in[5];
  const float* C_b     = (const float*)d_in[6];
  const float* A_log   = (const float*)d_in[7];
  const float* dt_bias = (const float*)d_in[8];
  const float* tau     = (const float*)d_in[9];
  const float* Wi_W    = (const float*)d_in[10];
  const float* Wi_b    = (const float*)d_in[11];
  const float* Wr_W    = (const float*)d_in[12];
  const float* sel_W   = (const float*)d_in[13];
  const float* sel_b   = (const float*)d_in[14];
  const float* h0      = (const float*)d_in[15];
  float* out = (float*)d_out;

  // ws layout (~37.3 MB): xb stays live through scan3 (no aliasing with scans).
  float* ws    = (float*)d_ws;
  float* delta = ws;                    // 4,194,304 f
  float* selp  = delta + 4194304;       // 2,048
  float* Bm    = selp + 2048;           // 65,536
  float* Cm    = Bm + 65536;            // 65,536
  u16*   xb    = (u16*)(Cm + 65536);    // 4,194,304 u16 (8 MB)
  u16*   Wp    = xb + 4194304;          // 2,228,224 u16 (4.25 MB)
  float* hin   = (float*)(Wp + 2228224);// 2,097,152 f (8 MB)
  float* part1 = hin;                   // 524,288  — dead before scan2 writes hin
  float* part2 = hin + 524288;          // 32,768   — dead before scan2
  // prodA/hend live in d_out (poisoned by harness; scan3 fully rewrites out).
  float* prodA = out;                   // 2,097,152 f
  float* hend  = out + 2097152;         // 2,097,152 f

  hipLaunchKernelGGL(k_gc_pack, dim3(512), dim3(256), 0, stream, x, part1, xb);
  hipLaunchKernelGGL(k_gc_red, dim3(128), dim3(256), 0, stream, part1, part2);
  hipLaunchKernelGGL(k_newh_sel, dim3(1), dim3(256), 0, stream,
                     part2, Wi_W, Wi_b, Wr_W, tau, h0, sel_W, sel_b, selp);
  hipLaunchKernelGGL(k_pack_w, dim3(544, 2), dim3(256), 0, stream,
                     deltaW, B_W, C_W, selp, Wp);
  hipLaunchKernelGGL(k_gemm, dim3(64, 17), dim3(256), 0, stream,
                     xb, Wp, deltab, dt_bias, B_b, C_b, delta, Bm, Cm);
  hipLaunchKernelGGL(k_scan1, dim3(2048), dim3(256), 0, stream,
                     xb, selp, delta, Bm, A_log, prodA, hend);
  hipLaunchKernelGGL(k_scan2, dim3(128), dim3(256), 0, stream,
                     prodA, hend, hin);
  hipLaunchKernelGGL(k_scan3, dim3(2048), dim3(256), 0, stream,
                     xb, selp, delta, Bm, Cm, A_log, hin, out);
}

// Round 14
// 138.538 us; speedup vs baseline: 1.0057x; 1.0057x over previous
//
#include <hip/hip_runtime.h>
#include <hip/hip_bf16.h>
#include <math.h>

#define B_ 2
#define L_ 2048
#define D_ 1024
#define N_ 16
#define CCH 128  // chunks over L
#define TCH 16   // chunk length  (CCH*TCH == L_)
#define NCOLS 1056   // D_ + 2*N_
#define NPAD  1088   // 17 * 64

typedef unsigned short u16;
typedef __attribute__((ext_vector_type(8))) short short8v;
typedef __attribute__((ext_vector_type(8))) unsigned short ushort8v;
typedef __attribute__((ext_vector_type(4))) float f32x4;

__device__ __forceinline__ float softplusf(float z) {
  return fmaxf(z, 0.f) + log1pf(__expf(-fabsf(z)));
}

__device__ __forceinline__ u16 bf16rne(float f) {
  union { float f; unsigned u; } c; c.f = f;
  unsigned u = c.u;
  u += 0x7fffu + ((u >> 16) & 1u);
  return (u16)(u >> 16);
}

__device__ __forceinline__ float bf16tof(u16 v) {
  union { unsigned u; float f; } c;
  c.u = (unsigned)v << 16;
  return c.f;
}

__device__ __forceinline__ void gl_lds16(const void* g, const u16* lds_base,
                                         int byte_off) {
  byte_off = __builtin_amdgcn_readfirstlane(byte_off);
  __builtin_amdgcn_global_load_lds(
      (const __attribute__((address_space(1))) void*)g,
      (__attribute__((address_space(3))) void*)((const char*)lds_base + byte_off),
      16, 0, 0);
}

// ------------- K1: fused gc partial-sum + x -> bf16 pack ---------------------
__global__ __launch_bounds__(256) void k_gc_pack(const float* __restrict__ x,
    float* __restrict__ part1, u16* __restrict__ xb) {
  int blk = blockIdx.x;
  int b = blk >> 8, lc = blk & 255;
  int tid = threadIdx.x;
  int r0 = b * L_ + lc * 8;
  float4 s = {0.f, 0.f, 0.f, 0.f};
  #pragma unroll
  for (int q = 0; q < 8; ++q) {
    size_t off = (size_t)(r0 + q) * D_ + tid * 4;
    float4 v = *(const float4*)(x + off);
    s.x += v.x; s.y += v.y; s.z += v.z; s.w += v.w;
    ushort4 r;
    r.x = bf16rne(v.x); r.y = bf16rne(v.y);
    r.z = bf16rne(v.z); r.w = bf16rne(v.w);
    *(ushort4*)(xb + off) = r;
  }
  *(float4*)(part1 + (size_t)blk * D_ + tid * 4) = s;
}

// ------------- K1b: reduce part1[512][1024] -> part2[2][16][1024] ------------
__global__ __launch_bounds__(256) void k_gc_red(const float* __restrict__ part1,
                                                float* __restrict__ part2) {
  int gid = blockIdx.x * 256 + threadIdx.x;   // 32768 = (b, jc, d)
  int d = gid & 1023;
  int jc = (gid >> 10) & 15;
  int b = gid >> 14;
  float s = 0.f;
  #pragma unroll
  for (int t = 0; t < 16; ++t)
    s += part1[(size_t)(b * 256 + jc * 16 + t) * D_ + d];
  part2[gid] = s;
}

// ------------- K2: gc -> liquid scaler -> new_h -> sel (fused) ---------------
__global__ __launch_bounds__(256) void k_newh_sel(const float* __restrict__ part2,
    const float* __restrict__ Wi_W, const float* __restrict__ Wi_b,
    const float* __restrict__ Wr_W, const float* __restrict__ tau,
    const float* __restrict__ h0, const float* __restrict__ sel_W,
    const float* __restrict__ sel_b, float* __restrict__ selp) {
  __shared__ float gcs[B_ * D_];
  __shared__ float nh[B_ * N_];
  int tid = threadIdx.x;
  for (int idx = tid; idx < B_ * D_; idx += 256) {
    int b = idx >> 10, d = idx & (D_ - 1);
    float s = 0.f;
    #pragma unroll
    for (int lc = 0; lc < 16; ++lc)
      s += part2[(size_t)((b << 4) | lc) * D_ + d];
    gcs[idx] = s * (1.f / L_);
  }
  __syncthreads();
  if (tid < B_ * N_) {
    int b = tid >> 4, n = tid & 15;
    float inp = Wi_b[n];
    const float* g = gcs + b * D_;
    const float* w = Wi_W + n * D_;
    for (int d = 0; d < D_; d += 4) {
      float4 gv = *(const float4*)(g + d);
      float4 wv = *(const float4*)(w + d);
      inp += gv.x * wv.x + gv.y * wv.y + gv.z * wv.z + gv.w * wv.w;
    }
    float rec = 0.f;
    for (int m = 0; m < N_; ++m) rec += h0[m] * Wr_W[n * N_ + m];
    float th = tanhf(inp + rec);
    float tc = fminf(fmaxf(tau[n], 0.1f), 10.f);
    float cur = h0[n];
    nh[tid] = cur + 0.1f * ((th - cur) / tc);   // DT = 0.1
  }
  __syncthreads();
  for (int i = tid; i < B_ * D_; i += 256) {
    int b = i >> 10, d = i & (D_ - 1);
    const float* w = sel_W + d * N_;
    const float* h = nh + b * N_;
    float z = sel_b[d];
    #pragma unroll
    for (int n = 0; n < N_; n += 4) {
      float4 wv = *(const float4*)(w + n);
      z += h[n] * wv.x + h[n + 1] * wv.y + h[n + 2] * wv.z + h[n + 3] * wv.w;
    }
    selp[i] = 1.f / (1.f + __expf(-z));
  }
}

// ------------- K4: pack [delta_W; B_W; C_W] * sel(b) -> bf16 -----------------
__global__ __launch_bounds__(256) void k_pack_w(const float* __restrict__ dW,
    const float* __restrict__ B_W, const float* __restrict__ C_W,
    const float* __restrict__ sel, u16* __restrict__ Wp) {
  int gid = blockIdx.x * 256 + threadIdx.x;    // 139264 threads, 8 elems each
  int b = blockIdx.y;
  size_t e = (size_t)gid * 8;                  // < 1114112
  int nn = (int)(e >> 10);
  int k = (int)(e & 1023);
  ushort8v r;
  if (nn < NCOLS) {
    const float* src = (nn < 1024) ? dW + (size_t)nn * 1024
                     : (nn < 1040) ? B_W + (size_t)(nn - 1024) * 1024
                                   : C_W + (size_t)(nn - 1040) * 1024;
    float4 s0 = *(const float4*)(src + k);
    float4 s1 = *(const float4*)(src + k + 4);
    const float* sp = sel + b * D_ + k;
    float4 e0 = *(const float4*)sp;
    float4 e1 = *(const float4*)(sp + 4);
    r[0] = bf16rne(s0.x * e0.x); r[1] = bf16rne(s0.y * e0.y);
    r[2] = bf16rne(s0.z * e0.z); r[3] = bf16rne(s0.w * e0.w);
    r[4] = bf16rne(s1.x * e1.x); r[5] = bf16rne(s1.y * e1.y);
    r[6] = bf16rne(s1.z * e1.z); r[7] = bf16rne(s1.w * e1.w);
  } else {
    r = (ushort8v)0;
  }
  *(ushort8v*)(Wp + (size_t)b * (NPAD * 1024) + e) = r;
}

// ------------- K5: MFMA GEMM  C[4096 x 1088] = xb @ Wp^T ---------------------
// R8-exact proven config: 64x64 tile, BK=64, 2-buffer counted vmcnt(4),
// XOR swizzle, linear block mapping, 32 KB LDS (~5 blocks/CU).
__global__ __launch_bounds__(256) void k_gemm(
    const u16* __restrict__ xb, const u16* __restrict__ Wp,
    const float* __restrict__ delta_b, const float* __restrict__ dt_bias,
    const float* __restrict__ B_b, const float* __restrict__ C_b,
    float* __restrict__ delta, float* __restrict__ Bm, float* __restrict__ Cm) {
  __shared__ __align__(16) u16 lds[4][4096];   // At0,At1,Bt0,Bt1 (8 KB each)
  int m0 = blockIdx.x * 64;
  int n0 = blockIdx.y * 64;
  int batch = blockIdx.x >> 5;                 // 32 m-tiles per batch
  const u16* wb = Wp + (size_t)batch * (NPAD * 1024);
  int tid = threadIdx.x;
  int w = tid >> 6, l = tid & 63;
  int wr = w >> 1, wc = w & 1;
  int srow = l >> 3;
  int ssl = (l & 7) ^ srow;

  f32x4 acc[2][2];
  #pragma unroll
  for (int m = 0; m < 2; ++m)
    #pragma unroll
    for (int n = 0; n < 2; ++n)
      acc[m][n] = (f32x4){0.f, 0.f, 0.f, 0.f};

  #define STAGE(kb, buf)                                                       \
    {                                                                          \
      _Pragma("unroll")                                                        \
      for (int q = 0; q < 2; ++q) {                                            \
        int row = w * 16 + q * 8 + srow;                                       \
        gl_lds16(xb + (size_t)(m0 + row) * 1024 + (kb) * 64 + ssl * 8,         \
                 &lds[0][0], (buf) * 8192 + (w * 16 + q * 8) * 128);           \
        gl_lds16(wb + (size_t)(n0 + row) * 1024 + (kb) * 64 + ssl * 8,         \
                 &lds[0][0], 16384 + (buf) * 8192 + (w * 16 + q * 8) * 128);   \
      }                                                                        \
    }

  int lr = l & 15, lh = l >> 4;

  #define CSTEP(cur)                                                           \
    {                                                                          \
      _Pragma("unroll")                                                        \
      for (int ks = 0; ks < 2; ++ks) {                                         \
        short8v a[2], bq[2];                                                   \
        _Pragma("unroll")                                                      \
        for (int m = 0; m < 2; ++m) {                                          \
          int r = wr * 32 + m * 16 + lr;                                       \
          int ps = (ks * 4 + lh) ^ (r & 7);                                    \
          a[m] = *(const short8v*)((const char*)&lds[0][0] + (cur) * 8192 + r * 128 + ps * 16);\
        }                                                                      \
        _Pragma("unroll")                                                      \
        for (int n = 0; n < 2; ++n) {                                          \
          int r = wc * 32 + n * 16 + lr;                                       \
          int ps = (ks * 4 + lh) ^ (r & 7);                                    \
          bq[n] = *(const short8v*)((const char*)&lds[0][0] + 16384 + (cur) * 8192 + r * 128 + ps * 16);\
        }                                                                      \
        _Pragma("unroll")                                                      \
        for (int m = 0; m < 2; ++m)                                            \
          _Pragma("unroll")                                                    \
          for (int n = 0; n < 2; ++n)                                          \
            acc[m][n] = __builtin_amdgcn_mfma_f32_16x16x32_bf16(a[m], bq[n],   \
                                                                acc[m][n], 0, 0, 0);\
      }                                                                        \
    }

  STAGE(0, 0);
  STAGE(1, 1);
  #pragma unroll
  for (int kb = 0; kb < 15; ++kb) {
    int cur = kb & 1;
    asm volatile("s_waitcnt vmcnt(4)" ::: "memory");   // tile kb staged
    __builtin_amdgcn_s_barrier();
    CSTEP(cur);
    asm volatile("s_waitcnt lgkmcnt(0)" ::: "memory");
    __builtin_amdgcn_s_barrier();
    if (kb < 14) STAGE(kb + 2, cur);
  }
  asm volatile("s_waitcnt vmcnt(0)" ::: "memory");
  __builtin_amdgcn_s_barrier();
  CSTEP(1);
  #undef STAGE
  #undef CSTEP

  int ibase = m0 + wr * 32 + lh * 4;
  int jbase = n0 + wc * 32 + lr;
  #pragma unroll
  for (int m = 0; m < 2; ++m) {
    #pragma unroll
    for (int n = 0; n < 2; ++n) {
      int j = jbase + n * 16;
      #pragma unroll
      for (int r = 0; r < 2 * 2; ++r) {
        int i = ibase + m * 16 + r;
        float v = acc[m][n][r];
        if (j < 1024) {
          delta[(size_t)i * D_ + j] = softplusf(v + delta_b[j] + dt_bias[j]);
        } else if (j < 1040) {
          Bm[i * N_ + (j - 1024)] = v + B_b[j - 1024];
        } else if (j < NCOLS) {
          Cm[i * N_ + (j - 1040)] = v + C_b[j - 1040];
        }
      }
    }
  }
}

// ------------- K6: scan pass 1 — local scan + sum(delta) ---------------------
// 4-way N-split, CCH=128 (16-step chains, 4096 blocks). Emits hend + sdelta
// (exp identity: prod_s exp(A*d_s) == exp(A*sum d_s) — validated R11).
__global__ __launch_bounds__(256) void k_scan1(const u16* __restrict__ xb,
    const float* __restrict__ sel, const float* __restrict__ delta,
    const float* __restrict__ Bm, const float* __restrict__ A_log,
    float* __restrict__ sdelta, float* __restrict__ hend) {
  int gid = blockIdx.x * 256 + threadIdx.x;   // ((b*CCH+c)*D + d)*4 + nq
  int nq = gid & 3;
  int d = (gid >> 2) & (D_ - 1);
  int c = (gid >> 12) & (CCH - 1);
  int b = gid >> 19;
  float A[4], rA[4];
  unsigned smallm = 0;
  {
    float4 a0 = *(const float4*)(A_log + d * N_ + nq * 4);
    float av[4] = {a0.x, a0.y, a0.z, a0.w};
    #pragma unroll
    for (int n = 0; n < 4; ++n) {
      float a = -__expf(av[n]);
      A[n] = a; rA[n] = 1.f / a;
      if (fabsf(a) < 1e-6f) smallm |= (1u << n);
    }
  }
  float selv = sel[b * D_ + d];
  float h[4];
  float sdl = 0.f;
  #pragma unroll
  for (int n = 0; n < 4; ++n) h[n] = 0.f;
  int row0 = b * L_ + c * TCH;
  const u16* xp = xb + (size_t)row0 * D_ + d;
  const float* dp = delta + (size_t)row0 * D_ + d;
  const float4* bmp = (const float4*)(Bm + (size_t)row0 * N_) + nq;
  #pragma unroll 4
  for (int s = 0; s < TCH; ++s) {
    float dlt = dp[(size_t)s * D_];
    float xv = bf16tof(xp[(size_t)s * D_]) * selv;
    sdl += dlt;
    float4 q0 = bmp[s * 4];
    float bmv[4] = {q0.x, q0.y, q0.z, q0.w};
    #pragma unroll
    for (int n = 0; n < 4; ++n) {
      float Ad = __expf(A[n] * dlt);
      float f = ((smallm >> n) & 1u) ? dlt : (Ad - 1.f) * rA[n];
      h[n] = Ad * h[n] + (f * bmv[n]) * xv;
    }
  }
  size_t base = ((size_t)(gid >> 2)) * N_ + nq * 4;
  *(float4*)(hend + base) = make_float4(h[0], h[1], h[2], h[3]);
  if (nq == 0) sdelta[gid >> 2] = sdl;
}

// ------------- K7: scan pass 2 — cross-chunk prefix (per b,d,n) --------------
// 128 chunks; p reconstructed as exp(A * sum_delta).
__global__ __launch_bounds__(256) void k_scan2(const float* __restrict__ sdelta,
    const float* __restrict__ hend, const float* __restrict__ A_log,
    float* __restrict__ hin) {
  int gid = blockIdx.x * 256 + threadIdx.x;   // over B*D*N = 32768
  int b = gid >> 14;
  int rem = gid & 16383;                      // d*N + n
  int d = rem >> 4;
  float a = -__expf(A_log[rem]);
  size_t hbase = ((size_t)(b * CCH) << 14) + rem;
  const float* sdp = sdelta + (size_t)b * (CCH * D_) + d;
  float H = 0.f;
  #pragma unroll
  for (int g = 0; g < 16; ++g) {
    float sd[8], hg[8];
    #pragma unroll
    for (int t = 0; t < 8; ++t) {
      int c = g * 8 + t;
      sd[t] = sdp[(size_t)c * D_];
      hg[t] = hend[hbase + ((size_t)c << 14)];
    }
    #pragma unroll
    for (int t = 0; t < 8; ++t) {
      int c = g * 8 + t;
      hin[hbase + ((size_t)c << 14)] = H;
      H = __expf(a * sd[t]) * H + hg[t];
    }
  }
}

// ------------- K8: scan pass 3 — re-scan with carry-in, emit y ---------------
// 4-way N-split, CCH=128; y reduced via shfl_xor(1), shfl_xor(2).
__global__ __launch_bounds__(256) void k_scan3(const u16* __restrict__ xb,
    const float* __restrict__ sel, const float* __restrict__ delta,
    const float* __restrict__ Bm, const float* __restrict__ Cm,
    const float* __restrict__ A_log, const float* __restrict__ hin,
    float* __restrict__ out) {
  int gid = blockIdx.x * 256 + threadIdx.x;   // 1048576 threads
  int nq = gid & 3;
  int d = (gid >> 2) & (D_ - 1);
  int c = (gid >> 12) & (CCH - 1);
  int b = gid >> 19;
  float A[4], rA[4];
  unsigned smallm = 0;
  {
    float4 a0 = *(const float4*)(A_log + d * N_ + nq * 4);
    float av[4] = {a0.x, a0.y, a0.z, a0.w};
    #pragma unroll
    for (int n = 0; n < 4; ++n) {
      float a = -__expf(av[n]);
      A[n] = a; rA[n] = 1.f / a;
      if (fabsf(a) < 1e-6f) smallm |= (1u << n);
    }
  }
  float selv = sel[b * D_ + d];
  float h[4];
  {
    size_t base = ((size_t)(gid >> 2)) * N_ + nq * 4;
    float4 v0 = *(const float4*)(hin + base);
    h[0] = v0.x; h[1] = v0.y; h[2] = v0.z; h[3] = v0.w;
  }
  int row0 = b * L_ + c * TCH;
  const u16* xp = xb + (size_t)row0 * D_ + d;
  const float* dp = delta + (size_t)row0 * D_ + d;
  const float4* bmp = (const float4*)(Bm + (size_t)row0 * N_) + nq;
  const float4* cmp = (const float4*)(Cm + (size_t)row0 * N_) + nq;
  float* op = out + (size_t)row0 * D_ + d;
  #pragma unroll 4
  for (int s = 0; s < TCH; ++s) {
    float dlt = dp[(size_t)s * D_];
    float xv = bf16tof(xp[(size_t)s * D_]) * selv;
    float4 q0 = bmp[s * 4];
    float4 r0 = cmp[s * 4];
    float bmv[4] = {q0.x, q0.y, q0.z, q0.w};
    float cmv[4] = {r0.x, r0.y, r0.z, r0.w};
    float yp = 0.f;
    #pragma unroll
    for (int n = 0; n < 4; ++n) {
      float Ad = __expf(A[n] * dlt);
      float f = ((smallm >> n) & 1u) ? dlt : (Ad - 1.f) * rA[n];
      h[n] = Ad * h[n] + (f * bmv[n]) * xv;
      yp += h[n] * cmv[n];
    }
    float y = yp + __shfl_xor(yp, 1, 64);
    y += __shfl_xor(y, 2, 64);
    if (nq == 0) op[(size_t)s * D_] = y;
  }
}

extern "C" void kernel_launch(void* const* d_in, const int* in_sizes, int n_in,
                              void* d_out, int out_size, void* d_ws, size_t ws_size,
                              hipStream_t stream) {
  const float* x       = (const float*)d_in[0];
  const float* deltaW  = (const float*)d_in[1];
  const float* deltab  = (const float*)d_in[2];
  const float* B_W     = (const float*)d_in[3];
  const float* B_b     = (const float*)d_in[4];
  const float* C_W     = (const float*)d_in[5];
  const float* C_b     = (const float*)d_in[6];
  const float* A_log   = (const float*)d_in[7];
  const float* dt_bias = (const float*)d_in[8];
  const float* tau     = (const float*)d_in[9];
  const float* Wi_W    = (const float*)d_in[10];
  const float* Wi_b    = (const float*)d_in[11];
  const float* Wr_W    = (const float*)d_in[12];
  const float* sel_W   = (const float*)d_in[13];
  const float* sel_b   = (const float*)d_in[14];
  const float* h0      = (const float*)d_in[15];
  float* out = (float*)d_out;

  // ws layout (~45.6 MB). hend (16 MB) lives in d_out; scan3 rewrites out.
  float* ws    = (float*)d_ws;
  float* delta = ws;                    // 4,194,304 f (16 MB)
  float* selp  = delta + 4194304;       // 2,048
  float* Bm    = selp + 2048;           // 65,536
  float* Cm    = Bm + 65536;            // 65,536
  u16*   xb    = (u16*)(Cm + 65536);    // 4,194,304 u16 (8 MB)
  u16*   Wp    = xb + 4194304;          // 2,228,224 u16 (4.25 MB)
  float* sdelta= (float*)(Wp + 2228224);// 262,144 (1 MB)
  float* hin   = sdelta + 262144;       // 4,194,304 f (16 MB)
  float* part1 = hin;                   // 524,288 — dead before scan2 writes hin
  float* part2 = hin + 524288;          // 32,768  — dead before scan2
  float* hend  = out;                   // 4,194,304 f in d_out (== out_size)

  hipLaunchKernelGGL(k_gc_pack, dim3(512), dim3(256), 0, stream, x, part1, xb);
  hipLaunchKernelGGL(k_gc_red, dim3(128), dim3(256), 0, stream, part1, part2);
  hipLaunchKernelGGL(k_newh_sel, dim3(1), dim3(256), 0, stream,
                     part2, Wi_W, Wi_b, Wr_W, tau, h0, sel_W, sel_b, selp);
  hipLaunchKernelGGL(k_pack_w, dim3(544, 2), dim3(256), 0, stream,
                     deltaW, B_W, C_W, selp, Wp);
  hipLaunchKernelGGL(k_gemm, dim3(64, 17), dim3(256), 0, stream,
                     xb, Wp, deltab, dt_bias, B_b, C_b, delta, Bm, Cm);
  hipLaunchKernelGGL(k_scan1, dim3(4096), dim3(256), 0, stream,
                     xb, selp, delta, Bm, A_log, sdelta, hend);
  hipLaunchKernelGGL(k_scan2, dim3(128), dim3(256), 0, stream,
                     sdelta, hend, A_log, hin);
  hipLaunchKernelGGL(k_scan3, dim3(4096), dim3(256), 0, stream,
                     xb, selp, delta, Bm, Cm, A_log, hin, out);
}

// Round 15
// 129.667 us; speedup vs baseline: 1.0745x; 1.0684x over previous
//
#include <hip/hip_runtime.h>
#include <hip/hip_bf16.h>
#include <math.h>

#define B_ 2
#define L_ 2048
#define D_ 1024
#define N_ 16
#define CCH 64   // chunks over L
#define TCH 32   // chunk length  (CCH*TCH == L_)
#define NCOLS 1056   // D_ + 2*N_
#define NPAD  1088   // 17 * 64

typedef unsigned short u16;
typedef __attribute__((ext_vector_type(8))) short short8v;
typedef __attribute__((ext_vector_type(8))) unsigned short ushort8v;
typedef __attribute__((ext_vector_type(4))) float f32x4;

__device__ __forceinline__ float softplusf(float z) {
  return fmaxf(z, 0.f) + log1pf(__expf(-fabsf(z)));
}

__device__ __forceinline__ u16 bf16rne(float f) {
  union { float f; unsigned u; } c; c.f = f;
  unsigned u = c.u;
  u += 0x7fffu + ((u >> 16) & 1u);
  return (u16)(u >> 16);
}

__device__ __forceinline__ float bf16tof(u16 v) {
  union { unsigned u; float f; } c;
  c.u = (unsigned)v << 16;
  return c.f;
}

__device__ __forceinline__ void gl_lds16(const void* g, const u16* lds_base,
                                         int byte_off) {
  byte_off = __builtin_amdgcn_readfirstlane(byte_off);
  __builtin_amdgcn_global_load_lds(
      (const __attribute__((address_space(1))) void*)g,
      (__attribute__((address_space(3))) void*)((const char*)lds_base + byte_off),
      16, 0, 0);
}

// ------------- K1: fused gc partial-sum + x -> bf16 pack ---------------------
__global__ __launch_bounds__(256) void k_gc_pack(const float* __restrict__ x,
    float* __restrict__ part1, u16* __restrict__ xb) {
  int blk = blockIdx.x;
  int b = blk >> 8, lc = blk & 255;
  int tid = threadIdx.x;
  int r0 = b * L_ + lc * 8;
  float4 s = {0.f, 0.f, 0.f, 0.f};
  #pragma unroll
  for (int q = 0; q < 8; ++q) {
    size_t off = (size_t)(r0 + q) * D_ + tid * 4;
    float4 v = *(const float4*)(x + off);
    s.x += v.x; s.y += v.y; s.z += v.z; s.w += v.w;
    ushort4 r;
    r.x = bf16rne(v.x); r.y = bf16rne(v.y);
    r.z = bf16rne(v.z); r.w = bf16rne(v.w);
    *(ushort4*)(xb + off) = r;
  }
  *(float4*)(part1 + (size_t)blk * D_ + tid * 4) = s;
}

// ------------- K1b: reduce part1[512][1024] -> part2[2][16][1024] ------------
__global__ __launch_bounds__(256) void k_gc_red(const float* __restrict__ part1,
                                                float* __restrict__ part2) {
  int gid = blockIdx.x * 256 + threadIdx.x;   // 32768 = (b, jc, d)
  int d = gid & 1023;
  int jc = (gid >> 10) & 15;
  int b = gid >> 14;
  float s = 0.f;
  #pragma unroll
  for (int t = 0; t < 16; ++t)
    s += part1[(size_t)(b * 256 + jc * 16 + t) * D_ + d];
  part2[gid] = s;
}

// ------------- K2: gc -> liquid scaler -> new_h -> sel (fused) ---------------
__global__ __launch_bounds__(256) void k_newh_sel(const float* __restrict__ part2,
    const float* __restrict__ Wi_W, const float* __restrict__ Wi_b,
    const float* __restrict__ Wr_W, const float* __restrict__ tau,
    const float* __restrict__ h0, const float* __restrict__ sel_W,
    const float* __restrict__ sel_b, float* __restrict__ selp) {
  __shared__ float gcs[B_ * D_];
  __shared__ float nh[B_ * N_];
  int tid = threadIdx.x;
  for (int idx = tid; idx < B_ * D_; idx += 256) {
    int b = idx >> 10, d = idx & (D_ - 1);
    float s = 0.f;
    #pragma unroll
    for (int lc = 0; lc < 16; ++lc)
      s += part2[(size_t)((b << 4) | lc) * D_ + d];
    gcs[idx] = s * (1.f / L_);
  }
  __syncthreads();
  if (tid < B_ * N_) {
    int b = tid >> 4, n = tid & 15;
    float inp = Wi_b[n];
    const float* g = gcs + b * D_;
    const float* w = Wi_W + n * D_;
    for (int d = 0; d < D_; d += 4) {
      float4 gv = *(const float4*)(g + d);
      float4 wv = *(const float4*)(w + d);
      inp += gv.x * wv.x + gv.y * wv.y + gv.z * wv.z + gv.w * wv.w;
    }
    float rec = 0.f;
    for (int m = 0; m < N_; ++m) rec += h0[m] * Wr_W[n * N_ + m];
    float th = tanhf(inp + rec);
    float tc = fminf(fmaxf(tau[n], 0.1f), 10.f);
    float cur = h0[n];
    nh[tid] = cur + 0.1f * ((th - cur) / tc);   // DT = 0.1
  }
  __syncthreads();
  for (int i = tid; i < B_ * D_; i += 256) {
    int b = i >> 10, d = i & (D_ - 1);
    const float* w = sel_W + d * N_;
    const float* h = nh + b * N_;
    float z = sel_b[d];
    #pragma unroll
    for (int n = 0; n < N_; n += 4) {
      float4 wv = *(const float4*)(w + n);
      z += h[n] * wv.x + h[n + 1] * wv.y + h[n + 2] * wv.z + h[n + 3] * wv.w;
    }
    selp[i] = 1.f / (1.f + __expf(-z));
  }
}

// ------------- K4: pack [delta_W; B_W; C_W] * sel(b) -> bf16 -----------------
__global__ __launch_bounds__(256) void k_pack_w(const float* __restrict__ dW,
    const float* __restrict__ B_W, const float* __restrict__ C_W,
    const float* __restrict__ sel, u16* __restrict__ Wp) {
  int gid = blockIdx.x * 256 + threadIdx.x;    // 139264 threads, 8 elems each
  int b = blockIdx.y;
  size_t e = (size_t)gid * 8;                  // < 1114112
  int nn = (int)(e >> 10);
  int k = (int)(e & 1023);
  ushort8v r;
  if (nn < NCOLS) {
    const float* src = (nn < 1024) ? dW + (size_t)nn * 1024
                     : (nn < 1040) ? B_W + (size_t)(nn - 1024) * 1024
                                   : C_W + (size_t)(nn - 1040) * 1024;
    float4 s0 = *(const float4*)(src + k);
    float4 s1 = *(const float4*)(src + k + 4);
    const float* sp = sel + b * D_ + k;
    float4 e0 = *(const float4*)sp;
    float4 e1 = *(const float4*)(sp + 4);
    r[0] = bf16rne(s0.x * e0.x); r[1] = bf16rne(s0.y * e0.y);
    r[2] = bf16rne(s0.z * e0.z); r[3] = bf16rne(s0.w * e0.w);
    r[4] = bf16rne(s1.x * e1.x); r[5] = bf16rne(s1.y * e1.y);
    r[6] = bf16rne(s1.z * e1.z); r[7] = bf16rne(s1.w * e1.w);
  } else {
    r = (ushort8v)0;
  }
  *(ushort8v*)(Wp + (size_t)b * (NPAD * 1024) + e) = r;
}

// ------------- K5: MFMA GEMM  C[4096 x 1088] = xb @ Wp^T ---------------------
// R8/R10-proven config: 64x64 tile, BK=64, 2-buffer counted vmcnt(4),
// XOR swizzle, linear block mapping, 32 KB LDS (~5 blocks/CU).
__global__ __launch_bounds__(256) void k_gemm(
    const u16* __restrict__ xb, const u16* __restrict__ Wp,
    const float* __restrict__ delta_b, const float* __restrict__ dt_bias,
    const float* __restrict__ B_b, const float* __restrict__ C_b,
    float* __restrict__ delta, float* __restrict__ Bm, float* __restrict__ Cm) {
  __shared__ __align__(16) u16 lds[4][4096];   // At0,At1,Bt0,Bt1 (8 KB each)
  int m0 = blockIdx.x * 64;
  int n0 = blockIdx.y * 64;
  int batch = blockIdx.x >> 5;                 // 32 m-tiles per batch
  const u16* wb = Wp + (size_t)batch * (NPAD * 1024);
  int tid = threadIdx.x;
  int w = tid >> 6, l = tid & 63;
  int wr = w >> 1, wc = w & 1;
  int srow = l >> 3;
  int ssl = (l & 7) ^ srow;

  f32x4 acc[2][2];
  #pragma unroll
  for (int m = 0; m < 2; ++m)
    #pragma unroll
    for (int n = 0; n < 2; ++n)
      acc[m][n] = (f32x4){0.f, 0.f, 0.f, 0.f};

  #define STAGE(kb, buf)                                                       \
    {                                                                          \
      _Pragma("unroll")                                                        \
      for (int q = 0; q < 2; ++q) {                                            \
        int row = w * 16 + q * 8 + srow;                                       \
        gl_lds16(xb + (size_t)(m0 + row) * 1024 + (kb) * 64 + ssl * 8,         \
                 &lds[0][0], (buf) * 8192 + (w * 16 + q * 8) * 128);           \
        gl_lds16(wb + (size_t)(n0 + row) * 1024 + (kb) * 64 + ssl * 8,         \
                 &lds[0][0], 16384 + (buf) * 8192 + (w * 16 + q * 8) * 128);   \
      }                                                                        \
    }

  int lr = l & 15, lh = l >> 4;

  #define CSTEP(cur)                                                           \
    {                                                                          \
      _Pragma("unroll")                                                        \
      for (int ks = 0; ks < 2; ++ks) {                                         \
        short8v a[2], bq[2];                                                   \
        _Pragma("unroll")                                                      \
        for (int m = 0; m < 2; ++m) {                                          \
          int r = wr * 32 + m * 16 + lr;                                       \
          int ps = (ks * 4 + lh) ^ (r & 7);                                    \
          a[m] = *(const short8v*)((const char*)&lds[0][0] + (cur) * 8192 + r * 128 + ps * 16);\
        }                                                                      \
        _Pragma("unroll")                                                      \
        for (int n = 0; n < 2; ++n) {                                          \
          int r = wc * 32 + n * 16 + lr;                                       \
          int ps = (ks * 4 + lh) ^ (r & 7);                                    \
          bq[n] = *(const short8v*)((const char*)&lds[0][0] + 16384 + (cur) * 8192 + r * 128 + ps * 16);\
        }                                                                      \
        _Pragma("unroll")                                                      \
        for (int m = 0; m < 2; ++m)                                            \
          _Pragma("unroll")                                                    \
          for (int n = 0; n < 2; ++n)                                          \
            acc[m][n] = __builtin_amdgcn_mfma_f32_16x16x32_bf16(a[m], bq[n],   \
                                                                acc[m][n], 0, 0, 0);\
      }                                                                        \
    }

  STAGE(0, 0);
  STAGE(1, 1);
  #pragma unroll
  for (int kb = 0; kb < 15; ++kb) {
    int cur = kb & 1;
    asm volatile("s_waitcnt vmcnt(4)" ::: "memory");   // tile kb staged
    __builtin_amdgcn_s_barrier();
    CSTEP(cur);
    asm volatile("s_waitcnt lgkmcnt(0)" ::: "memory");
    __builtin_amdgcn_s_barrier();
    if (kb < 14) STAGE(kb + 2, cur);
  }
  asm volatile("s_waitcnt vmcnt(0)" ::: "memory");
  __builtin_amdgcn_s_barrier();
  CSTEP(1);
  #undef STAGE
  #undef CSTEP

  int ibase = m0 + wr * 32 + lh * 4;
  int jbase = n0 + wc * 32 + lr;
  #pragma unroll
  for (int m = 0; m < 2; ++m) {
    #pragma unroll
    for (int n = 0; n < 2; ++n) {
      int j = jbase + n * 16;
      #pragma unroll
      for (int r = 0; r < 2 * 2; ++r) {
        int i = ibase + m * 16 + r;
        float v = acc[m][n][r];
        if (j < 1024) {
          delta[(size_t)i * D_ + j] = softplusf(v + delta_b[j] + dt_bias[j]);
        } else if (j < 1040) {
          Bm[i * N_ + (j - 1024)] = v + B_b[j - 1024];
        } else if (j < NCOLS) {
          Cm[i * N_ + (j - 1040)] = v + C_b[j - 1040];
        }
      }
    }
  }
}

// ------------- K6: scan pass 1 — local scan + decay product ------------------
// 4-way N-split; reads bf16 xb (L2-resident). 2048 blocks, streaming.
__global__ __launch_bounds__(256) void k_scan1(const u16* __restrict__ xb,
    const float* __restrict__ sel, const float* __restrict__ delta,
    const float* __restrict__ Bm, const float* __restrict__ A_log,
    float* __restrict__ prodA, float* __restrict__ hend) {
  int gid = blockIdx.x * 256 + threadIdx.x;   // ((b*CCH+c)*D + d)*4 + nq
  int nq = gid & 3;
  int d = (gid >> 2) & (D_ - 1);
  int c = (gid >> 12) & (CCH - 1);
  int b = gid >> 18;
  float A[4], rA[4];
  unsigned smallm = 0;
  {
    float4 a0 = *(const float4*)(A_log + d * N_ + nq * 4);
    float av[4] = {a0.x, a0.y, a0.z, a0.w};
    #pragma unroll
    for (int n = 0; n < 4; ++n) {
      float a = -__expf(av[n]);
      A[n] = a; rA[n] = 1.f / a;
      if (fabsf(a) < 1e-6f) smallm |= (1u << n);
    }
  }
  float selv = sel[b * D_ + d];
  float h[4], p[4];
  #pragma unroll
  for (int n = 0; n < 4; ++n) { h[n] = 0.f; p[n] = 1.f; }
  int row0 = b * L_ + c * TCH;
  const u16* xp = xb + (size_t)row0 * D_ + d;
  const float* dp = delta + (size_t)row0 * D_ + d;
  const float4* bmp = (const float4*)(Bm + (size_t)row0 * N_) + nq;
  #pragma unroll 4
  for (int s = 0; s < TCH; ++s) {
    float dlt = dp[(size_t)s * D_];
    float xv = bf16tof(xp[(size_t)s * D_]) * selv;
    float4 q0 = bmp[s * 4];
    float bmv[4] = {q0.x, q0.y, q0.z, q0.w};
    #pragma unroll
    for (int n = 0; n < 4; ++n) {
      float Ad = __expf(A[n] * dlt);
      float f = ((smallm >> n) & 1u) ? dlt : (Ad - 1.f) * rA[n];
      h[n] = Ad * h[n] + (f * bmv[n]) * xv;
      p[n] *= Ad;
    }
  }
  size_t base = ((size_t)(gid >> 2)) * N_ + nq * 4;
  *(float4*)(prodA + base) = make_float4(p[0], p[1], p[2], p[3]);
  *(float4*)(hend + base)  = make_float4(h[0], h[1], h[2], h[3]);
}

// ------------- K7: scan pass 2 — cross-chunk prefix (per b,d,n) --------------
__global__ __launch_bounds__(256) void k_scan2(const float* __restrict__ prodA,
    const float* __restrict__ hend, float* __restrict__ hin) {
  int gid = blockIdx.x * 256 + threadIdx.x;   // over B*D*N = 32768
  int b = gid >> 14;
  int rem = gid & 16383;
  size_t base = ((size_t)(b * CCH) << 14) + rem;
  float H = 0.f;
  #pragma unroll
  for (int g = 0; g < 4; ++g) {
    float pg[16], hg[16];
    #pragma unroll
    for (int t = 0; t < 16; ++t) {
      size_t idx = base + ((size_t)(g * 16 + t) << 14);
      pg[t] = prodA[idx];
      hg[t] = hend[idx];
    }
    #pragma unroll
    for (int t = 0; t < 16; ++t) {
      size_t idx = base + ((size_t)(g * 16 + t) << 14);
      hin[idx] = H;
      H = pg[t] * H + hg[t];
    }
  }
}

// ------------- K8: scan pass 3 — re-scan with carry-in, emit y ---------------
// 4-way N-split; reads bf16 xb; y reduced via shfl_xor(1), shfl_xor(2).
__global__ __launch_bounds__(256) void k_scan3(const u16* __restrict__ xb,
    const float* __restrict__ sel, const float* __restrict__ delta,
    const float* __restrict__ Bm, const float* __restrict__ Cm,
    const float* __restrict__ A_log, const float* __restrict__ hin,
    float* __restrict__ out) {
  int gid = blockIdx.x * 256 + threadIdx.x;   // 524288 threads
  int nq = gid & 3;
  int d = (gid >> 2) & (D_ - 1);
  int c = (gid >> 12) & (CCH - 1);
  int b = gid >> 18;
  float A[4], rA[4];
  unsigned smallm = 0;
  {
    float4 a0 = *(const float4*)(A_log + d * N_ + nq * 4);
    float av[4] = {a0.x, a0.y, a0.z, a0.w};
    #pragma unroll
    for (int n = 0; n < 4; ++n) {
      float a = -__expf(av[n]);
      A[n] = a; rA[n] = 1.f / a;
      if (fabsf(a) < 1e-6f) smallm |= (1u << n);
    }
  }
  float selv = sel[b * D_ + d];
  float h[4];
  {
    size_t base = ((size_t)(gid >> 2)) * N_ + nq * 4;
    float4 v0 = *(const float4*)(hin + base);
    h[0] = v0.x; h[1] = v0.y; h[2] = v0.z; h[3] = v0.w;
  }
  int row0 = b * L_ + c * TCH;
  const u16* xp = xb + (size_t)row0 * D_ + d;
  const float* dp = delta + (size_t)row0 * D_ + d;
  const float4* bmp = (const float4*)(Bm + (size_t)row0 * N_) + nq;
  const float4* cmp = (const float4*)(Cm + (size_t)row0 * N_) + nq;
  float* op = out + (size_t)row0 * D_ + d;
  #pragma unroll 4
  for (int s = 0; s < TCH; ++s) {
    float dlt = dp[(size_t)s * D_];
    float xv = bf16tof(xp[(size_t)s * D_]) * selv;
    float4 q0 = bmp[s * 4];
    float4 r0 = cmp[s * 4];
    float bmv[4] = {q0.x, q0.y, q0.z, q0.w};
    float cmv[4] = {r0.x, r0.y, r0.z, r0.w};
    float yp = 0.f;
    #pragma unroll
    for (int n = 0; n < 4; ++n) {
      float Ad = __expf(A[n] * dlt);
      float f = ((smallm >> n) & 1u) ? dlt : (Ad - 1.f) * rA[n];
      h[n] = Ad * h[n] + (f * bmv[n]) * xv;
      yp += h[n] * cmv[n];
    }
    float y = yp + __shfl_xor(yp, 1, 64);
    y += __shfl_xor(y, 2, 64);
    if (nq == 0) op[(size_t)s * D_] = y;
  }
}

extern "C" void kernel_launch(void* const* d_in, const int* in_sizes, int n_in,
                              void* d_out, int out_size, void* d_ws, size_t ws_size,
                              hipStream_t stream) {
  const float* x       = (const float*)d_in[0];
  const float* deltaW  = (const float*)d_in[1];
  const float* deltab  = (const float*)d_in[2];
  const float* B_W     = (const float*)d_in[3];
  const float* B_b     = (const float*)d_in[4];
  const float* C_W     = (const float*)d_in[5];
  const float* C_b     = (const float*)d_in[6];
  const float* A_log   = (const float*)d_in[7];
  const float* dt_bias = (const float*)d_in[8];
  const float* tau     = (const float*)d_in[9];
  const float* Wi_W    = (const float*)d_in[10];
  const float* Wi_b    = (const float*)d_in[11];
  const float* Wr_W    = (const float*)d_in[12];
  const float* sel_W   = (const float*)d_in[13];
  const float* sel_b   = (const float*)d_in[14];
  const float* h0      = (const float*)d_in[15];
  float* out = (float*)d_out;

  // ws layout (~37.3 MB): xb stays live through scan3 (no aliasing with scans).
  float* ws    = (float*)d_ws;
  float* delta = ws;                    // 4,194,304 f
  float* selp  = delta + 4194304;       // 2,048
  float* Bm    = selp + 2048;           // 65,536
  float* Cm    = Bm + 65536;            // 65,536
  u16*   xb    = (u16*)(Cm + 65536);    // 4,194,304 u16 (8 MB)
  u16*   Wp    = xb + 4194304;          // 2,228,224 u16 (4.25 MB)
  float* hin   = (float*)(Wp + 2228224);// 2,097,152 f (8 MB)
  float* part1 = hin;                   // 524,288  — dead before scan2 writes hin
  float* part2 = hin + 524288;          // 32,768   — dead before scan2
  // prodA/hend live in d_out (poisoned by harness; scan3 fully rewrites out).
  float* prodA = out;                   // 2,097,152 f
  float* hend  = out + 2097152;         // 2,097,152 f

  hipLaunchKernelGGL(k_gc_pack, dim3(512), dim3(256), 0, stream, x, part1, xb);
  hipLaunchKernelGGL(k_gc_red, dim3(128), dim3(256), 0, stream, part1, part2);
  hipLaunchKernelGGL(k_newh_sel, dim3(1), dim3(256), 0, stream,
                     part2, Wi_W, Wi_b, Wr_W, tau, h0, sel_W, sel_b, selp);
  hipLaunchKernelGGL(k_pack_w, dim3(544, 2), dim3(256), 0, stream,
                     deltaW, B_W, C_W, selp, Wp);
  hipLaunchKernelGGL(k_gemm, dim3(64, 17), dim3(256), 0, stream,
                     xb, Wp, deltab, dt_bias, B_b, C_b, delta, Bm, Cm);
  hipLaunchKernelGGL(k_scan1, dim3(2048), dim3(256), 0, stream,
                     xb, selp, delta, Bm, A_log, prodA, hend);
  hipLaunchKernelGGL(k_scan2, dim3(128), dim3(256), 0, stream,
                     prodA, hend, hin);
  hipLaunchKernelGGL(k_scan3, dim3(2048), dim3(256), 0, stream,
                     xb, selp, delta, Bm, Cm, A_log, hin, out);
}